// Round 7
// baseline (178.406 us; speedup 1.0000x reference)
//
#include <hip/hip_runtime.h>

// Problem constants: B=2, T=2048, C=1024, H=16, HS=64
typedef unsigned short u16;
typedef unsigned int u32;
typedef __bf16 bf16x8 __attribute__((ext_vector_type(8)));
typedef float f32x4 __attribute__((ext_vector_type(4)));
typedef u16 u16x4 __attribute__((ext_vector_type(4)));
typedef u16 u16x8 __attribute__((ext_vector_type(8)));

__device__ __forceinline__ u16 f2bf(float f) {
  u32 u = __builtin_bit_cast(u32, f);
  u += 0x7fffu + ((u >> 16) & 1u);   // round-to-nearest-even
  return (u16)(u >> 16);
}

// pack two f32 -> two bf16 (round-half-up) in one u32; a in low half.
__device__ __forceinline__ u32 pk2(float a, float b) {
  u32 ua = __builtin_bit_cast(u32, a) + 0x8000u;
  u32 ub = __builtin_bit_cast(u32, b) + 0x8000u;
  return __builtin_amdgcn_perm(ub, ua, 0x07060302);  // {ub.hi16, ua.hi16}
}

__device__ __forceinline__ void gld16(const void* g, void* l) {
  __builtin_amdgcn_global_load_lds(
      (const __attribute__((address_space(1))) void*)g,
      (__attribute__((address_space(3))) void*)l, 16, 0, 0);
}

// ---------------- merged prep kernel (one launch) ----------------
__global__ __launch_bounds__(256) void k_prep(
    const float* __restrict__ x, u16* __restrict__ xb,
    const float* __restrict__ Wqkv, u16* __restrict__ Wqkvt,
    const float* __restrict__ Wproj, u16* __restrict__ Wpt,
    float2* __restrict__ rope) {
  __shared__ float tile[32][33];
  const int tid = threadIdx.x;
  int bx = blockIdx.x;
  if (bx < 4096) {
    int i = (bx * 256 + tid) * 4;
    float4 v = *(const float4*)(x + i);
    u16x4 o = { f2bf(v.x), f2bf(v.y), f2bf(v.z), f2bf(v.w) };
    *(u16x4*)(xb + i) = o;
    return;
  }
  bx -= 4096;
  const float* src; u16* dst; int R, Cc, bxx, byy;
  if (bx < 3072) {
    src = Wqkv; dst = Wqkvt; R = 1024; Cc = 3072; bxx = bx % 96; byy = bx / 96;
  } else if (bx < 4096) {
    int b = bx - 3072;
    src = Wproj; dst = Wpt; R = 1024; Cc = 1024; bxx = b % 32; byy = b / 32;
  } else {
    int i = (bx - 4096) * 256 + tid;  // 0..65535
    int t = i >> 5, d = i & 31;
    float theta = expf(-(float)d * 0.28782313662425575f);  // ln(10000)/32
    float ang = (float)t * theta;
    rope[i] = make_float2(cosf(ang), sinf(ang));
    return;
  }
  int xx = tid & 31, yy = tid >> 5;
  int c0 = bxx * 32, r0 = byy * 32;
  for (int i = 0; i < 4; ++i)
    tile[yy + 8 * i][xx] = src[(size_t)(r0 + yy + 8 * i) * Cc + c0 + xx];
  __syncthreads();
  for (int i = 0; i < 4; ++i)
    dst[(size_t)(c0 + yy + 8 * i) * R + r0 + xx] = f2bf(tile[xx][yy + 8 * i]);
}

// --------------- QKV GEMM + bias + RoPE + scatter ---------------
__global__ __launch_bounds__(256, 4) void k_qkv(
    const u16* __restrict__ Xb,      // [4096][1024] bf16
    const u16* __restrict__ Wt,      // [3072][1024] bf16 (W_qkv^T)
    const float* __restrict__ bias,  // [3072]
    const float2* __restrict__ rope, // [2048][32]
    u16* __restrict__ Qg,            // [B,H,T,HS]
    u16* __restrict__ Kg,            // [B,H,T,HS]
    u16* __restrict__ Vt) {          // [B,H,HS,T]
  __shared__ alignas(16) u16 smem[18432];  // 36 KB: As|Bs in K-loop, Es after
  u16* As = smem;           // [128][64]
  u16* Bs = smem + 8192;    // [128][64]
  const int tid = threadIdx.x;
  const int lane = tid & 63, w = tid >> 6;
  const int quad = lane >> 4, l15 = lane & 15;
  const int m0 = blockIdx.y * 128, n0 = blockIdx.x * 128;
  const int wm = (w & 1) * 64, wn = (w >> 1) * 64;
  const int srow = lane >> 3, sj = lane & 7;
  const int sw = (sj ^ srow) * 8;   // swizzled source u16 offset
  const f32x4 vzero = {0.f, 0.f, 0.f, 0.f};

  f32x4 acc[4][4];  // [nt][mt] (swapped order)
  for (int i = 0; i < 4; ++i)
    for (int j = 0; j < 4; ++j) acc[i][j] = vzero;

  for (int kt = 0; kt < 1024; kt += 64) {
    __syncthreads();
    for (int i = 0; i < 4; ++i) {
      int row = w * 32 + i * 8;
      gld16(Xb + (size_t)(m0 + row + srow) * 1024 + kt + sw, &As[row * 64]);
      gld16(Wt + (size_t)(n0 + row + srow) * 1024 + kt + sw, &Bs[row * 64]);
    }
    __syncthreads();
    for (int ks = 0; ks < 2; ++ks) {
      const int cc = ((ks * 4 + quad) ^ (l15 & 7)) * 8;
      bf16x8 a[4], b[4];
      for (int mt = 0; mt < 4; ++mt)
        a[mt] = *(const bf16x8*)&As[(wm + mt * 16 + l15) * 64 + cc];
      for (int nt = 0; nt < 4; ++nt)
        b[nt] = *(const bf16x8*)&Bs[(wn + nt * 16 + l15) * 64 + cc];
      for (int nt = 0; nt < 4; ++nt)
        for (int mt = 0; mt < 4; ++mt)
          acc[nt][mt] = __builtin_amdgcn_mfma_f32_16x16x32_bf16(
              b[nt], a[mt], acc[nt][mt], 0, 0, 0);
    }
  }
  __syncthreads();  // all waves done reading As/Bs; safe to overwrite with Es

  // ---- stage into LDS (bias + RoPE applied), wave-uniform region per half
  const int half = w >> 1;
  const int nh = n0 + half * 64;             // 64-aligned -> single region
  const int region = (nh % 192) >> 6;        // 0=Q 1=K 2=V
  u16* Eh = smem + half * 9216;
  if (region < 2) {
    // lane: m = wm + mt*16 + l15; quad*4+r = 4 consecutive hs
    for (int nt = 0; nt < 4; ++nt) {
      float4 bv4 = *(const float4*)&bias[nh + nt * 16 + quad * 4];
      for (int mt = 0; mt < 4; ++mt) {
        int m_l = wm + mt * 16 + l15;
        int t = (m0 + m_l) & 2047;
        float4 cs = *(const float4*)&rope[t * 32 + nt * 8 + quad * 2];
        float v0 = acc[nt][mt][0] + bv4.x;
        float v1 = acc[nt][mt][1] + bv4.y;
        float v2 = acc[nt][mt][2] + bv4.z;
        float v3 = acc[nt][mt][3] + bv4.w;
        float r0 = fmaf(-v1, cs.y, v0 * cs.x);
        float r1 = fmaf( v0, cs.y, v1 * cs.x);
        float r2 = fmaf(-v3, cs.w, v2 * cs.z);
        float r3 = fmaf( v2, cs.w, v3 * cs.z);
        uint2 pv; pv.x = pk2(r0, r1); pv.y = pk2(r2, r3);
        *(uint2*)&Eh[m_l * 72 + nt * 16 + quad * 4] = pv;
      }
    }
  } else {
    // V: transposed [c][m] stride 136; c = nt*16+quad*4+r varies with r
    for (int nt = 0; nt < 4; ++nt) {
      float4 bv4 = *(const float4*)&bias[nh + nt * 16 + quad * 4];
      for (int mt = 0; mt < 4; ++mt) {
        int m_l = wm + mt * 16 + l15;
        int cb = nt * 16 + quad * 4;
        Eh[(cb + 0) * 136 + m_l] = f2bf(acc[nt][mt][0] + bv4.x);
        Eh[(cb + 1) * 136 + m_l] = f2bf(acc[nt][mt][1] + bv4.y);
        Eh[(cb + 2) * 136 + m_l] = f2bf(acc[nt][mt][2] + bv4.z);
        Eh[(cb + 3) * 136 + m_l] = f2bf(acc[nt][mt][3] + bv4.w);
      }
    }
  }
  __syncthreads();

  // ---- coalesced write-out: 16 B per lane
  const int bb = m0 >> 11, t0 = m0 & 2047;
  for (int hf = 0; hf < 2; ++hf) {
    const int nhf = n0 + hf * 64;
    const int hh = nhf / 192;
    const int reg = (nhf % 192) >> 6;
    const u16* Ef = smem + hf * 9216;
    if (reg < 2) {
      u16* dst = (reg == 0 ? Qg : Kg) +
                 ((size_t)(bb * 16 + hh) * 2048 + t0) * 64;
      int chunk = tid & 7, row0 = tid >> 3;
      for (int p = 0; p < 4; ++p) {
        int row = row0 + p * 32;
        u16x8 val = *(const u16x8*)&Ef[row * 72 + chunk * 8];
        *(u16x8*)(dst + (size_t)row * 64 + chunk * 8) = val;
      }
    } else {
      u16* dstv = Vt + (size_t)(bb * 16 + hh) * 64 * 2048 + t0;
      int mch = tid & 15, c0r = tid >> 4;
      for (int p = 0; p < 4; ++p) {
        int c = c0r + p * 16;
        u16x8 val = *(const u16x8*)&Ef[c * 136 + mch * 8];
        *(u16x8*)(dstv + (size_t)c * 2048 + mch * 8) = val;
      }
    }
  }
}

// ------------------- flash attention (causal) -------------------
// grid (16, 32 bh), 256 threads = 4 waves. BQ=64, BKV=64, dbuf KV.
// UNIFORM work: block bx processes q-tiles {bx, 31-bx} sequentially ->
// (bx+1) + (32-bx) = 33 KV-block iterations for EVERY block (zero tail).
// S^T = K·Q^T; packed b64 P-writes; no-max softmax; deferred l.
__global__ __launch_bounds__(256, 4) void k_attn(
    const u16* __restrict__ Qg, const u16* __restrict__ Kg,
    const u16* __restrict__ Vt, u16* __restrict__ Og) {  // Og: [4096][1024] bf16
  __shared__ alignas(16) u16 Ks[2][64 * 64];
  __shared__ alignas(16) u16 Vs[2][64 * 64];   // [hs][kk]
  __shared__ alignas(16) u16 Ps[64 * 72];
  const int tid = threadIdx.x, lane = tid & 63, w = tid >> 6;  // w in 0..3
  const int quad = lane >> 4, l15 = lane & 15;
  const int bh = blockIdx.y;
  const u16* Qh = Qg + (size_t)bh * 2048 * 64;
  const u16* Kh = Kg + (size_t)bh * 2048 * 64;
  const u16* Vh = Vt + (size_t)bh * 64 * 2048;
  const f32x4 vzero = {0.f, 0.f, 0.f, 0.f};
  const float SCL = 0.125f * 1.4426950408889634f;  // 1/sqrt(64) * log2(e)
  const int myrow = w * 16;
  const int bb = bh >> 4, h = bh & 15;

  // staging source swizzle: lane (r8,j) fetches global chunk j^r8 of its row
  const int r8 = lane >> 3, j8 = lane & 7;
  const int sw_c = (j8 ^ r8) * 8;

  // prologue: stage k-block 0 into buffer 0 (each wave stages 16 rows)
  for (int i = 0; i < 2; ++i) {
    int row = w * 16 + i * 8;
    gld16(Kh + (size_t)(row + r8) * 64 + sw_c, &Ks[0][row * 64]);
    gld16(Vh + (size_t)(row + r8) * 2048 + sw_c, &Vs[0][row * 64]);
  }

  int buf = 0;
  const int tiles[2] = {(int)blockIdx.x, 31 - (int)blockIdx.x};
  for (int ti = 0; ti < 2; ++ti) {
    const int qt = tiles[ti];
    const int q0 = qt * 64;
    // Q fragments direct to registers (row = q0 + myrow + l15)
    bf16x8 aq[2];
    {
      const u16* qp = Qh + (size_t)(q0 + myrow + l15) * 64 + quad * 8;
      aq[0] = *(const bf16x8*)(qp);
      aq[1] = *(const bf16x8*)(qp + 32);
    }
    float lsum = 0.f;
    f32x4 O[4];
    for (int nt = 0; nt < 4; ++nt) O[nt] = vzero;

    const int nk = qt + 1;
    for (int kb = 0; kb < nk; ++kb) {
      const int k0 = kb * 64;
      __syncthreads();  // buf staged+visible; buf^1 readers (prev iter) done
      // prefetch next KV block (crosses tile boundary to k=0 of next tile)
      int nxt = (kb + 1 < nk) ? (k0 + 64) : (ti == 0 ? 0 : -1);
      if (nxt >= 0) {
        for (int i = 0; i < 2; ++i) {
          int row = w * 16 + i * 8;
          gld16(Kh + (size_t)(nxt + row + r8) * 64 + sw_c, &Ks[buf ^ 1][row * 64]);
          gld16(Vh + (size_t)(row + r8) * 2048 + nxt + sw_c, &Vs[buf ^ 1][row * 64]);
        }
      }

      // S^T = K Q^T : rows = k (64), cols = q (this wave's 16)
      f32x4 st[4];
      for (int nt = 0; nt < 4; ++nt) st[nt] = vzero;
      for (int ks = 0; ks < 2; ++ks) {
        bf16x8 ak[4];
        for (int nt = 0; nt < 4; ++nt)
          ak[nt] = *(const bf16x8*)&Ks[buf][(nt * 16 + l15) * 64 +
                                           ((ks * 4 + quad) ^ (l15 & 7)) * 8];
        for (int nt = 0; nt < 4; ++nt)
          st[nt] = __builtin_amdgcn_mfma_f32_16x16x32_bf16(ak[nt], aq[ks], st[nt], 0, 0, 0);
      }

      // p = exp2(s*SCL); pack 4 consecutive-k p's -> one ds_write_b64 per nt
      if (kb < qt) {  // fully unmasked block
        for (int nt = 0; nt < 4; ++nt) {
          float p0 = __builtin_amdgcn_exp2f(st[nt][0] * SCL);
          float p1 = __builtin_amdgcn_exp2f(st[nt][1] * SCL);
          float p2 = __builtin_amdgcn_exp2f(st[nt][2] * SCL);
          float p3 = __builtin_amdgcn_exp2f(st[nt][3] * SCL);
          lsum += (p0 + p1) + (p2 + p3);
          uint2 pv; pv.x = pk2(p0, p1); pv.y = pk2(p2, p3);
          *(uint2*)&Ps[(myrow + l15) * 72 + nt * 16 + quad * 4] = pv;
        }
      } else {  // diagonal block: mask k > tq
        const int tq = q0 + myrow + l15;     // this lane's q column
        const int kbase = k0 + quad * 4;
        for (int nt = 0; nt < 4; ++nt) {
          float p[4];
          for (int r = 0; r < 4; ++r) {
            float pv = __builtin_amdgcn_exp2f(st[nt][r] * SCL);
            p[r] = (kbase + nt * 16 + r <= tq) ? pv : 0.f;
            lsum += p[r];
          }
          uint2 pv; pv.x = pk2(p[0], p[1]); pv.y = pk2(p[2], p[3]);
          *(uint2*)&Ps[(myrow + l15) * 72 + nt * 16 + quad * 4] = pv;
        }
      }

      // O += P V  (Ps rows are wave-private; in-wave LDS order suffices)
      for (int ks = 0; ks < 2; ++ks) {
        bf16x8 a = *(const bf16x8*)&Ps[(myrow + l15) * 72 + ks * 32 + quad * 8];
        bf16x8 bv[4];
        for (int nt = 0; nt < 4; ++nt)
          bv[nt] = *(const bf16x8*)&Vs[buf][(nt * 16 + l15) * 64 +
                                           ((ks * 4 + quad) ^ (l15 & 7)) * 8];
        for (int nt = 0; nt < 4; ++nt)
          O[nt] = __builtin_amdgcn_mfma_f32_16x16x32_bf16(a, bv[nt], O[nt], 0, 0, 0);
      }
      buf ^= 1;
    }

    // deferred l reduction: lanes with same l15 across 4 quads hold partials
    float ls = lsum;
    ls += __shfl_xor(ls, 16, 64);
    ls += __shfl_xor(ls, 32, 64);
    float inv[4];
    for (int r = 0; r < 4; ++r)
      inv[r] = 1.0f / __shfl(ls, quad * 4 + r, 16);  // l for q-row quad*4+r

    // epilogue: normalize, stage via Ps (stride 72), coalesced 16 B stores
    for (int nt = 0; nt < 4; ++nt)
      for (int r = 0; r < 4; ++r)
        Ps[(myrow + quad * 4 + r) * 72 + nt * 16 + l15] = f2bf(O[nt][r] * inv[r]);
    __syncthreads();
    u16* dst = Og + ((size_t)bb * 2048 + q0) * 1024 + h * 64;
    int chunk = tid & 7, row0 = tid >> 3;   // 32 rows x 8 chunks
    for (int p = 0; p < 2; ++p) {
      int row = row0 + p * 32;
      u16x8 val = *(const u16x8*)&Ps[row * 72 + chunk * 8];
      *(u16x8*)(dst + (size_t)row * 1024 + chunk * 8) = val;
    }
    // next tile's top-of-loop barrier protects Ps reuse
  }
}

// --------------------- output projection GEMM ---------------------
// BM=64, BN=128, BK=64, swizzled staging. grid (8, 64) = 512 blocks (2/CU).
__global__ __launch_bounds__(256, 4) void k_proj(
    const u16* __restrict__ Ag,      // [4096][1024] bf16
    const u16* __restrict__ Wt,      // [1024][1024] bf16 (W_proj^T)
    const float* __restrict__ bias,  // [1024]
    float* __restrict__ out) {       // [4096][1024] f32
  __shared__ alignas(16) u16 As[64 * 64];
  __shared__ alignas(16) u16 Bs[128 * 64];
  const int tid = threadIdx.x;
  const int lane = tid & 63, w = tid >> 6;
  const int quad = lane >> 4, l15 = lane & 15;
  const int m0 = blockIdx.y * 64, n0 = blockIdx.x * 128;
  const int wm = (w & 1) * 32, wn = (w >> 1) * 64;
  const int srow = lane >> 3, sj = lane & 7;
  const int sw = (sj ^ srow) * 8;
  const f32x4 vzero = {0.f, 0.f, 0.f, 0.f};

  f32x4 acc[2][4];
  for (int i = 0; i < 2; ++i)
    for (int j = 0; j < 4; ++j) acc[i][j] = vzero;

  for (int kt = 0; kt < 1024; kt += 64) {
    __syncthreads();
    for (int i = 0; i < 2; ++i) {
      int row = w * 16 + i * 8;
      gld16(Ag + (size_t)(m0 + row + srow) * 1024 + kt + sw, &As[row * 64]);
    }
    for (int i = 0; i < 4; ++i) {
      int row = w * 32 + i * 8;
      gld16(Wt + (size_t)(n0 + row + srow) * 1024 + kt + sw, &Bs[row * 64]);
    }
    __syncthreads();
    for (int ks = 0; ks < 2; ++ks) {
      const int cc = ((ks * 4 + quad) ^ (l15 & 7)) * 8;
      bf16x8 a[2], b[4];
      for (int mt = 0; mt < 2; ++mt)
        a[mt] = *(const bf16x8*)&As[(wm + mt * 16 + l15) * 64 + cc];
      for (int nt = 0; nt < 4; ++nt)
        b[nt] = *(const bf16x8*)&Bs[(wn + nt * 16 + l15) * 64 + cc];
      for (int mt = 0; mt < 2; ++mt)
        for (int nt = 0; nt < 4; ++nt)
          acc[mt][nt] = __builtin_amdgcn_mfma_f32_16x16x32_bf16(
              a[mt], b[nt], acc[mt][nt], 0, 0, 0);
    }
  }

  for (int nt = 0; nt < 4; ++nt) {
    int n = n0 + wn + nt * 16 + l15;
    float bv = bias[n];
    for (int mt = 0; mt < 2; ++mt)
      for (int r = 0; r < 4; ++r) {
        int m = m0 + wm + mt * 16 + quad * 4 + r;
        out[(size_t)m * 1024 + n] = acc[mt][nt][r] + bv;
      }
  }
}

extern "C" void kernel_launch(void* const* d_in, const int* in_sizes, int n_in,
                              void* d_out, int out_size, void* d_ws, size_t ws_size,
                              hipStream_t stream) {
  (void)in_sizes; (void)n_in; (void)out_size; (void)ws_size;
  const float* x     = (const float*)d_in[0];
  const float* Wqkv  = (const float*)d_in[1];
  const float* bqkv  = (const float*)d_in[2];
  const float* Wproj = (const float*)d_in[3];
  const float* bproj = (const float*)d_in[4];
  float* out = (float*)d_out;

  char* ws = (char*)d_ws;
  size_t off = 0;
  u16* Xb    = (u16*)(ws + off); off += (size_t)4096 * 1024 * 2;   // x bf16
  u16* Wqkvt = (u16*)(ws + off); off += (size_t)3072 * 1024 * 2;   // W_qkv^T bf16
  u16* Wpt   = (u16*)(ws + off); off += (size_t)1024 * 1024 * 2;   // W_proj^T bf16
  u16* Qg    = (u16*)(ws + off); off += (size_t)2 * 16 * 2048 * 64 * 2;
  u16* Kg    = (u16*)(ws + off); off += (size_t)2 * 16 * 2048 * 64 * 2;
  u16* Vt    = (u16*)(ws + off); off += (size_t)2 * 16 * 64 * 2048 * 2;
  u16* Att   = (u16*)(ws + off); off += (size_t)4096 * 1024 * 2;
  float2* rope = (float2*)(ws + off); off += (size_t)2048 * 32 * sizeof(float2);

  k_prep<<<8448, 256, 0, stream>>>(x, Xb, Wqkv, Wqkvt, Wproj, Wpt, rope);
  k_qkv<<<dim3(24, 32), 256, 0, stream>>>(Xb, Wqkvt, bqkv, rope, Qg, Kg, Vt);
  k_attn<<<dim3(16, 32), 256, 0, stream>>>(Qg, Kg, Vt, Att);
  k_proj<<<dim3(8, 64), 256, 0, stream>>>(Att, Wpt, bproj, out);
}

// Round 8
// 167.800 us; speedup vs baseline: 1.0632x; 1.0632x over previous
//
#include <hip/hip_runtime.h>

// Problem constants: B=2, T=2048, C=1024, H=16, HS=64
typedef unsigned short u16;
typedef unsigned int u32;
typedef __bf16 bf16x8 __attribute__((ext_vector_type(8)));
typedef float f32x4 __attribute__((ext_vector_type(4)));
typedef u16 u16x4 __attribute__((ext_vector_type(4)));
typedef u16 u16x8 __attribute__((ext_vector_type(8)));

__device__ __forceinline__ u16 f2bf(float f) {
  u32 u = __builtin_bit_cast(u32, f);
  u += 0x7fffu + ((u >> 16) & 1u);   // round-to-nearest-even
  return (u16)(u >> 16);
}

// pack two f32 -> two bf16 (round-half-up) in one u32; a in low half.
__device__ __forceinline__ u32 pk2(float a, float b) {
  u32 ua = __builtin_bit_cast(u32, a) + 0x8000u;
  u32 ub = __builtin_bit_cast(u32, b) + 0x8000u;
  return __builtin_amdgcn_perm(ub, ua, 0x07060302);  // {ub.hi16, ua.hi16}
}

__device__ __forceinline__ void gld16(const void* g, void* l) {
  __builtin_amdgcn_global_load_lds(
      (const __attribute__((address_space(1))) void*)g,
      (__attribute__((address_space(3))) void*)l, 16, 0, 0);
}

// ---------------- merged prep kernel (one launch) ----------------
__global__ __launch_bounds__(256) void k_prep(
    const float* __restrict__ x, u16* __restrict__ xb,
    const float* __restrict__ Wqkv, u16* __restrict__ Wqkvt,
    const float* __restrict__ Wproj, u16* __restrict__ Wpt,
    float2* __restrict__ rope) {
  __shared__ float tile[32][33];
  const int tid = threadIdx.x;
  int bx = blockIdx.x;
  if (bx < 4096) {
    int i = (bx * 256 + tid) * 4;
    float4 v = *(const float4*)(x + i);
    u16x4 o = { f2bf(v.x), f2bf(v.y), f2bf(v.z), f2bf(v.w) };
    *(u16x4*)(xb + i) = o;
    return;
  }
  bx -= 4096;
  const float* src; u16* dst; int R, Cc, bxx, byy;
  if (bx < 3072) {
    src = Wqkv; dst = Wqkvt; R = 1024; Cc = 3072; bxx = bx % 96; byy = bx / 96;
  } else if (bx < 4096) {
    int b = bx - 3072;
    src = Wproj; dst = Wpt; R = 1024; Cc = 1024; bxx = b % 32; byy = b / 32;
  } else {
    int i = (bx - 4096) * 256 + tid;  // 0..65535
    int t = i >> 5, d = i & 31;
    float theta = expf(-(float)d * 0.28782313662425575f);  // ln(10000)/32
    float ang = (float)t * theta;
    rope[i] = make_float2(cosf(ang), sinf(ang));
    return;
  }
  int xx = tid & 31, yy = tid >> 5;
  int c0 = bxx * 32, r0 = byy * 32;
  for (int i = 0; i < 4; ++i)
    tile[yy + 8 * i][xx] = src[(size_t)(r0 + yy + 8 * i) * Cc + c0 + xx];
  __syncthreads();
  for (int i = 0; i < 4; ++i)
    dst[(size_t)(c0 + yy + 8 * i) * R + r0 + xx] = f2bf(tile[xx][yy + 8 * i]);
}

// --------------- QKV GEMM + bias + RoPE + scatter ---------------
__global__ __launch_bounds__(256, 4) void k_qkv(
    const u16* __restrict__ Xb,      // [4096][1024] bf16
    const u16* __restrict__ Wt,      // [3072][1024] bf16 (W_qkv^T)
    const float* __restrict__ bias,  // [3072]
    const float2* __restrict__ rope, // [2048][32]
    u16* __restrict__ Qg,            // [B,H,T,HS]
    u16* __restrict__ Kg,            // [B,H,T,HS]
    u16* __restrict__ Vt) {          // [B,H,HS,T]
  __shared__ alignas(16) u16 smem[18432];  // 36 KB: As|Bs in K-loop, Es after
  u16* As = smem;           // [128][64]
  u16* Bs = smem + 8192;    // [128][64]
  const int tid = threadIdx.x;
  const int lane = tid & 63, w = tid >> 6;
  const int quad = lane >> 4, l15 = lane & 15;
  const int m0 = blockIdx.y * 128, n0 = blockIdx.x * 128;
  const int wm = (w & 1) * 64, wn = (w >> 1) * 64;
  const int srow = lane >> 3, sj = lane & 7;
  const int sw = (sj ^ srow) * 8;   // swizzled source u16 offset
  const f32x4 vzero = {0.f, 0.f, 0.f, 0.f};

  f32x4 acc[4][4];  // [nt][mt] (swapped order)
  for (int i = 0; i < 4; ++i)
    for (int j = 0; j < 4; ++j) acc[i][j] = vzero;

  for (int kt = 0; kt < 1024; kt += 64) {
    __syncthreads();
    for (int i = 0; i < 4; ++i) {
      int row = w * 32 + i * 8;
      gld16(Xb + (size_t)(m0 + row + srow) * 1024 + kt + sw, &As[row * 64]);
      gld16(Wt + (size_t)(n0 + row + srow) * 1024 + kt + sw, &Bs[row * 64]);
    }
    __syncthreads();
    for (int ks = 0; ks < 2; ++ks) {
      const int cc = ((ks * 4 + quad) ^ (l15 & 7)) * 8;
      bf16x8 a[4], b[4];
      for (int mt = 0; mt < 4; ++mt)
        a[mt] = *(const bf16x8*)&As[(wm + mt * 16 + l15) * 64 + cc];
      for (int nt = 0; nt < 4; ++nt)
        b[nt] = *(const bf16x8*)&Bs[(wn + nt * 16 + l15) * 64 + cc];
      for (int nt = 0; nt < 4; ++nt)
        for (int mt = 0; mt < 4; ++mt)
          acc[nt][mt] = __builtin_amdgcn_mfma_f32_16x16x32_bf16(
              b[nt], a[mt], acc[nt][mt], 0, 0, 0);
    }
  }
  __syncthreads();  // all waves done reading As/Bs; safe to overwrite with Es

  // ---- stage into LDS (bias + RoPE applied), wave-uniform region per half
  const int half = w >> 1;
  const int nh = n0 + half * 64;             // 64-aligned -> single region
  const int region = (nh % 192) >> 6;        // 0=Q 1=K 2=V
  u16* Eh = smem + half * 9216;
  if (region < 2) {
    // lane: m = wm + mt*16 + l15; quad*4+r = 4 consecutive hs
    for (int nt = 0; nt < 4; ++nt) {
      float4 bv4 = *(const float4*)&bias[nh + nt * 16 + quad * 4];
      for (int mt = 0; mt < 4; ++mt) {
        int m_l = wm + mt * 16 + l15;
        int t = (m0 + m_l) & 2047;
        float4 cs = *(const float4*)&rope[t * 32 + nt * 8 + quad * 2];
        float v0 = acc[nt][mt][0] + bv4.x;
        float v1 = acc[nt][mt][1] + bv4.y;
        float v2 = acc[nt][mt][2] + bv4.z;
        float v3 = acc[nt][mt][3] + bv4.w;
        float r0 = fmaf(-v1, cs.y, v0 * cs.x);
        float r1 = fmaf( v0, cs.y, v1 * cs.x);
        float r2 = fmaf(-v3, cs.w, v2 * cs.z);
        float r3 = fmaf( v2, cs.w, v3 * cs.z);
        uint2 pv; pv.x = pk2(r0, r1); pv.y = pk2(r2, r3);
        *(uint2*)&Eh[m_l * 72 + nt * 16 + quad * 4] = pv;
      }
    }
  } else {
    // V: transposed [c][m] stride 136; c = nt*16+quad*4+r varies with r
    for (int nt = 0; nt < 4; ++nt) {
      float4 bv4 = *(const float4*)&bias[nh + nt * 16 + quad * 4];
      for (int mt = 0; mt < 4; ++mt) {
        int m_l = wm + mt * 16 + l15;
        int cb = nt * 16 + quad * 4;
        Eh[(cb + 0) * 136 + m_l] = f2bf(acc[nt][mt][0] + bv4.x);
        Eh[(cb + 1) * 136 + m_l] = f2bf(acc[nt][mt][1] + bv4.y);
        Eh[(cb + 2) * 136 + m_l] = f2bf(acc[nt][mt][2] + bv4.z);
        Eh[(cb + 3) * 136 + m_l] = f2bf(acc[nt][mt][3] + bv4.w);
      }
    }
  }
  __syncthreads();

  // ---- coalesced write-out: 16 B per lane
  const int bb = m0 >> 11, t0 = m0 & 2047;
  for (int hf = 0; hf < 2; ++hf) {
    const int nhf = n0 + hf * 64;
    const int hh = nhf / 192;
    const int reg = (nhf % 192) >> 6;
    const u16* Ef = smem + hf * 9216;
    if (reg < 2) {
      u16* dst = (reg == 0 ? Qg : Kg) +
                 ((size_t)(bb * 16 + hh) * 2048 + t0) * 64;
      int chunk = tid & 7, row0 = tid >> 3;
      for (int p = 0; p < 4; ++p) {
        int row = row0 + p * 32;
        u16x8 val = *(const u16x8*)&Ef[row * 72 + chunk * 8];
        *(u16x8*)(dst + (size_t)row * 64 + chunk * 8) = val;
      }
    } else {
      u16* dstv = Vt + (size_t)(bb * 16 + hh) * 64 * 2048 + t0;
      int mch = tid & 15, c0r = tid >> 4;
      for (int p = 0; p < 4; ++p) {
        int c = c0r + p * 16;
        u16x8 val = *(const u16x8*)&Ef[c * 136 + mch * 8];
        *(u16x8*)(dstv + (size_t)c * 2048 + mch * 8) = val;
      }
    }
  }
}

// ------------------- flash attention (causal) -------------------
// 1D grid of 512, 256 threads = 4 waves. BQ=64, BKV=64, dbuf KV.
// XCD-affinity decode: all 16 blocks of one bh share id%8 -> same XCD under
// round-robin dispatch -> that bh's 512 KB of KV stays in one 4 MB L2.
// UNIFORM work: block processes q-tiles {bx, 31-bx} sequentially -> 33 KV-block
// iterations for EVERY block. S^T = K·Q^T; packed b64 P-writes; no-max softmax.
__global__ __launch_bounds__(256, 4) void k_attn(
    const u16* __restrict__ Qg, const u16* __restrict__ Kg,
    const u16* __restrict__ Vt, u16* __restrict__ Og) {  // Og: [4096][1024] bf16
  __shared__ alignas(16) u16 Ks[2][64 * 64];
  __shared__ alignas(16) u16 Vs[2][64 * 64];   // [hs][kk]
  __shared__ alignas(16) u16 Ps[64 * 72];
  const int tid = threadIdx.x, lane = tid & 63, w = tid >> 6;  // w in 0..3
  const int quad = lane >> 4, l15 = lane & 15;
  // id = (bh%8) + 8*((bh/8)*16 + bx)  =>  decode:
  const int id = blockIdx.x;
  const int xr = id & 7, j = id >> 3;
  const int bx = j & 15;
  const int bh = (j >> 4) * 8 + xr;
  const u16* Qh = Qg + (size_t)bh * 2048 * 64;
  const u16* Kh = Kg + (size_t)bh * 2048 * 64;
  const u16* Vh = Vt + (size_t)bh * 64 * 2048;
  const f32x4 vzero = {0.f, 0.f, 0.f, 0.f};
  const float SCL = 0.125f * 1.4426950408889634f;  // 1/sqrt(64) * log2(e)
  const int myrow = w * 16;
  const int bb = bh >> 4, h = bh & 15;

  // staging source swizzle: lane (r8,j) fetches global chunk j^r8 of its row
  const int r8 = lane >> 3, j8 = lane & 7;
  const int sw_c = (j8 ^ r8) * 8;

  // prologue: stage k-block 0 into buffer 0 (each wave stages 16 rows)
  for (int i = 0; i < 2; ++i) {
    int row = w * 16 + i * 8;
    gld16(Kh + (size_t)(row + r8) * 64 + sw_c, &Ks[0][row * 64]);
    gld16(Vh + (size_t)(row + r8) * 2048 + sw_c, &Vs[0][row * 64]);
  }

  int buf = 0;
  const int tiles[2] = {bx, 31 - bx};
  for (int ti = 0; ti < 2; ++ti) {
    const int qt = tiles[ti];
    const int q0 = qt * 64;
    // Q fragments direct to registers (row = q0 + myrow + l15)
    bf16x8 aq[2];
    {
      const u16* qp = Qh + (size_t)(q0 + myrow + l15) * 64 + quad * 8;
      aq[0] = *(const bf16x8*)(qp);
      aq[1] = *(const bf16x8*)(qp + 32);
    }
    float lsum = 0.f;
    f32x4 O[4];
    for (int nt = 0; nt < 4; ++nt) O[nt] = vzero;

    const int nk = qt + 1;
    for (int kb = 0; kb < nk; ++kb) {
      const int k0 = kb * 64;
      __syncthreads();  // buf staged+visible; buf^1 readers (prev iter) done
      // prefetch next KV block (crosses tile boundary to k=0 of next tile)
      int nxt = (kb + 1 < nk) ? (k0 + 64) : (ti == 0 ? 0 : -1);
      if (nxt >= 0) {
        for (int i = 0; i < 2; ++i) {
          int row = w * 16 + i * 8;
          gld16(Kh + (size_t)(nxt + row + r8) * 64 + sw_c, &Ks[buf ^ 1][row * 64]);
          gld16(Vh + (size_t)(row + r8) * 2048 + nxt + sw_c, &Vs[buf ^ 1][row * 64]);
        }
      }

      // S^T = K Q^T : rows = k (64), cols = q (this wave's 16)
      f32x4 st[4];
      for (int nt = 0; nt < 4; ++nt) st[nt] = vzero;
      for (int ks = 0; ks < 2; ++ks) {
        bf16x8 ak[4];
        for (int nt = 0; nt < 4; ++nt)
          ak[nt] = *(const bf16x8*)&Ks[buf][(nt * 16 + l15) * 64 +
                                           ((ks * 4 + quad) ^ (l15 & 7)) * 8];
        for (int nt = 0; nt < 4; ++nt)
          st[nt] = __builtin_amdgcn_mfma_f32_16x16x32_bf16(ak[nt], aq[ks], st[nt], 0, 0, 0);
      }

      // p = exp2(s*SCL); pack 4 consecutive-k p's -> one ds_write_b64 per nt
      if (kb < qt) {  // fully unmasked block
        for (int nt = 0; nt < 4; ++nt) {
          float p0 = __builtin_amdgcn_exp2f(st[nt][0] * SCL);
          float p1 = __builtin_amdgcn_exp2f(st[nt][1] * SCL);
          float p2 = __builtin_amdgcn_exp2f(st[nt][2] * SCL);
          float p3 = __builtin_amdgcn_exp2f(st[nt][3] * SCL);
          lsum += (p0 + p1) + (p2 + p3);
          uint2 pv; pv.x = pk2(p0, p1); pv.y = pk2(p2, p3);
          *(uint2*)&Ps[(myrow + l15) * 72 + nt * 16 + quad * 4] = pv;
        }
      } else {  // diagonal block: mask k > tq
        const int tq = q0 + myrow + l15;     // this lane's q column
        const int kbase = k0 + quad * 4;
        for (int nt = 0; nt < 4; ++nt) {
          float p[4];
          for (int r = 0; r < 4; ++r) {
            float pv = __builtin_amdgcn_exp2f(st[nt][r] * SCL);
            p[r] = (kbase + nt * 16 + r <= tq) ? pv : 0.f;
            lsum += p[r];
          }
          uint2 pv; pv.x = pk2(p[0], p[1]); pv.y = pk2(p[2], p[3]);
          *(uint2*)&Ps[(myrow + l15) * 72 + nt * 16 + quad * 4] = pv;
        }
      }

      // O += P V  (Ps rows are wave-private; in-wave LDS order suffices)
      for (int ks = 0; ks < 2; ++ks) {
        bf16x8 a = *(const bf16x8*)&Ps[(myrow + l15) * 72 + ks * 32 + quad * 8];
        bf16x8 bv[4];
        for (int nt = 0; nt < 4; ++nt)
          bv[nt] = *(const bf16x8*)&Vs[buf][(nt * 16 + l15) * 64 +
                                           ((ks * 4 + quad) ^ (l15 & 7)) * 8];
        for (int nt = 0; nt < 4; ++nt)
          O[nt] = __builtin_amdgcn_mfma_f32_16x16x32_bf16(a, bv[nt], O[nt], 0, 0, 0);
      }
      buf ^= 1;
    }

    // deferred l reduction: lanes with same l15 across 4 quads hold partials
    float ls = lsum;
    ls += __shfl_xor(ls, 16, 64);
    ls += __shfl_xor(ls, 32, 64);
    float inv[4];
    for (int r = 0; r < 4; ++r)
      inv[r] = 1.0f / __shfl(ls, quad * 4 + r, 16);  // l for q-row quad*4+r

    // epilogue: normalize, stage via Ps (stride 72), coalesced 16 B stores
    for (int nt = 0; nt < 4; ++nt)
      for (int r = 0; r < 4; ++r)
        Ps[(myrow + quad * 4 + r) * 72 + nt * 16 + l15] = f2bf(O[nt][r] * inv[r]);
    __syncthreads();
    u16* dst = Og + ((size_t)bb * 2048 + q0) * 1024 + h * 64;
    int chunk = tid & 7, row0 = tid >> 3;   // 32 rows x 8 chunks
    for (int p = 0; p < 2; ++p) {
      int row = row0 + p * 32;
      u16x8 val = *(const u16x8*)&Ps[row * 72 + chunk * 8];
      *(u16x8*)(dst + (size_t)row * 1024 + chunk * 8) = val;
    }
    // next tile's top-of-loop barrier protects Ps reuse
  }
}

// --------------------- output projection GEMM ---------------------
// BM=64, BN=128, BK=64, swizzled staging. grid (8, 64) = 512 blocks (2/CU).
__global__ __launch_bounds__(256, 4) void k_proj(
    const u16* __restrict__ Ag,      // [4096][1024] bf16
    const u16* __restrict__ Wt,      // [1024][1024] bf16 (W_proj^T)
    const float* __restrict__ bias,  // [1024]
    float* __restrict__ out) {       // [4096][1024] f32
  __shared__ alignas(16) u16 As[64 * 64];
  __shared__ alignas(16) u16 Bs[128 * 64];
  const int tid = threadIdx.x;
  const int lane = tid & 63, w = tid >> 6;
  const int quad = lane >> 4, l15 = lane & 15;
  const int m0 = blockIdx.y * 64, n0 = blockIdx.x * 128;
  const int wm = (w & 1) * 32, wn = (w >> 1) * 64;
  const int srow = lane >> 3, sj = lane & 7;
  const int sw = (sj ^ srow) * 8;
  const f32x4 vzero = {0.f, 0.f, 0.f, 0.f};

  f32x4 acc[2][4];
  for (int i = 0; i < 2; ++i)
    for (int j = 0; j < 4; ++j) acc[i][j] = vzero;

  for (int kt = 0; kt < 1024; kt += 64) {
    __syncthreads();
    for (int i = 0; i < 2; ++i) {
      int row = w * 16 + i * 8;
      gld16(Ag + (size_t)(m0 + row + srow) * 1024 + kt + sw, &As[row * 64]);
    }
    for (int i = 0; i < 4; ++i) {
      int row = w * 32 + i * 8;
      gld16(Wt + (size_t)(n0 + row + srow) * 1024 + kt + sw, &Bs[row * 64]);
    }
    __syncthreads();
    for (int ks = 0; ks < 2; ++ks) {
      const int cc = ((ks * 4 + quad) ^ (l15 & 7)) * 8;
      bf16x8 a[2], b[4];
      for (int mt = 0; mt < 2; ++mt)
        a[mt] = *(const bf16x8*)&As[(wm + mt * 16 + l15) * 64 + cc];
      for (int nt = 0; nt < 4; ++nt)
        b[nt] = *(const bf16x8*)&Bs[(wn + nt * 16 + l15) * 64 + cc];
      for (int mt = 0; mt < 2; ++mt)
        for (int nt = 0; nt < 4; ++nt)
          acc[mt][nt] = __builtin_amdgcn_mfma_f32_16x16x32_bf16(
              a[mt], b[nt], acc[mt][nt], 0, 0, 0);
    }
  }

  for (int nt = 0; nt < 4; ++nt) {
    int n = n0 + wn + nt * 16 + l15;
    float bv = bias[n];
    for (int mt = 0; mt < 2; ++mt)
      for (int r = 0; r < 4; ++r) {
        int m = m0 + wm + mt * 16 + quad * 4 + r;
        out[(size_t)m * 1024 + n] = acc[mt][nt][r] + bv;
      }
  }
}

extern "C" void kernel_launch(void* const* d_in, const int* in_sizes, int n_in,
                              void* d_out, int out_size, void* d_ws, size_t ws_size,
                              hipStream_t stream) {
  (void)in_sizes; (void)n_in; (void)out_size; (void)ws_size;
  const float* x     = (const float*)d_in[0];
  const float* Wqkv  = (const float*)d_in[1];
  const float* bqkv  = (const float*)d_in[2];
  const float* Wproj = (const float*)d_in[3];
  const float* bproj = (const float*)d_in[4];
  float* out = (float*)d_out;

  char* ws = (char*)d_ws;
  size_t off = 0;
  u16* Xb    = (u16*)(ws + off); off += (size_t)4096 * 1024 * 2;   // x bf16
  u16* Wqkvt = (u16*)(ws + off); off += (size_t)3072 * 1024 * 2;   // W_qkv^T bf16
  u16* Wpt   = (u16*)(ws + off); off += (size_t)1024 * 1024 * 2;   // W_proj^T bf16
  u16* Qg    = (u16*)(ws + off); off += (size_t)2 * 16 * 2048 * 64 * 2;
  u16* Kg    = (u16*)(ws + off); off += (size_t)2 * 16 * 2048 * 64 * 2;
  u16* Vt    = (u16*)(ws + off); off += (size_t)2 * 16 * 64 * 2048 * 2;
  u16* Att   = (u16*)(ws + off); off += (size_t)4096 * 1024 * 2;
  float2* rope = (float2*)(ws + off); off += (size_t)2048 * 32 * sizeof(float2);

  k_prep<<<8448, 256, 0, stream>>>(x, Xb, Wqkv, Wqkvt, Wproj, Wpt, rope);
  k_qkv<<<dim3(24, 32), 256, 0, stream>>>(Xb, Wqkvt, bqkv, rope, Qg, Kg, Vt);
  k_attn<<<512, 256, 0, stream>>>(Qg, Kg, Vt, Att);
  k_proj<<<dim3(8, 64), 256, 0, stream>>>(Att, Wpt, bproj, out);
}